// Round 1
// baseline (343.021 us; speedup 1.0000x reference)
//
#include <hip/hip_runtime.h>
#include <stdint.h>

#define B_   4
#define S_   2048
#define D_   1024
#define NH_  16
#define HD_  64
#define D3   (3*D_)
#define TOK  (B_*S_)

typedef unsigned short u16;
typedef unsigned int   u32;
typedef float    f32x4  __attribute__((ext_vector_type(4)));
typedef __bf16   bf16x8 __attribute__((ext_vector_type(8)));
typedef u16      u16x8  __attribute__((ext_vector_type(8)));
typedef int      i32x4  __attribute__((ext_vector_type(4)));

#if __has_builtin(__builtin_amdgcn_exp2f)
#define EXP2(x) __builtin_amdgcn_exp2f(x)
#else
#define EXP2(x) exp2f(x)
#endif

// 0.125 (1/sqrt(64)) * log2(e): softmax on scaled logits via exp2
#define CSC 0.18033688011112042f

__device__ __forceinline__ u16 f2bf(float f){
  u32 x = __float_as_uint(f);
  x += 0x7fffu + ((x >> 16) & 1u);   // RNE; inputs are well-behaved (no NaN)
  return (u16)(x >> 16);
}

__device__ __forceinline__ u32 cvtpk(float lo, float hi){
  u32 r;
  asm("v_cvt_pk_bf16_f32 %0, %1, %2" : "=v"(r) : "v"(lo), "v"(hi));
  return r;
}

__device__ __forceinline__ void g2l16(const u16* g, u16* l){
  __builtin_amdgcn_global_load_lds((const __attribute__((address_space(1))) u32*)(g),
                                   (__attribute__((address_space(3))) u32*)(l), 16, 0, 0);
}

// ---------------- cast x (f32 -> bf16), 8 elems/thread ----------------
__global__ __launch_bounds__(256) void castx_kernel(const float* __restrict__ in,
                                                    u16* __restrict__ out){
  size_t i = ((size_t)blockIdx.x*256 + threadIdx.x)*8;
  f32x4 a = *(const f32x4*)(in + i);
  f32x4 b = *(const f32x4*)(in + i + 4);
  i32x4 v;
  v[0] = cvtpk(a[0], a[1]); v[1] = cvtpk(a[2], a[3]);
  v[2] = cvtpk(b[0], b[1]); v[3] = cvtpk(b[2], b[3]);
  *(i32x4*)(out + i) = v;
}

// ------------- transpose-cast W[K][N] f32 -> Wt[N][K] bf16 -------------
__global__ __launch_bounds__(256) void tcast_kernel(const float* __restrict__ in,
                                                    u16* __restrict__ out, int K, int N){
  __shared__ float tile[32][33];
  int i0 = blockIdx.x*32;          // K dim
  int j0 = blockIdx.y*32;          // N dim
  int t  = threadIdx.x;
  int cl = t & 31, rq = t >> 5;
  #pragma unroll
  for(int it=0; it<4; ++it){
    int r = rq + it*8;
    tile[r][cl] = in[(size_t)(i0 + r)*N + j0 + cl];
  }
  __syncthreads();
  #pragma unroll
  for(int it=0; it<4; ++it){
    int r = rq + it*8;             // n-local
    out[(size_t)(j0 + r)*K + i0 + cl] = f2bf(tile[cl][r]);
  }
}

// ------------- V transpose: qkv V-block -> Vt[b][h][d][s] bf16 -------------
__global__ __launch_bounds__(256) void vtrans_kernel(const u16* __restrict__ qkv,
                                                     u16* __restrict__ Vt){
  __shared__ __attribute__((aligned(16))) u16 tile[64*80];  // pad to 80 for alignment
  int st = blockIdx.x, h = blockIdx.y, b = blockIdx.z;
  int t = threadIdx.x;
  {
    int s = t >> 2, dc = t & 3;
    const u16* src = qkv + (size_t)(b*S_ + st*64 + s)*D3 + 2*D_ + h*HD_ + dc*16;
    *(u16x8*)&tile[s*80 + dc*16]     = *(const u16x8*)src;
    *(u16x8*)&tile[s*80 + dc*16 + 8] = *(const u16x8*)(src + 8);
  }
  __syncthreads();
  {
    int d = t >> 2, sc = t & 3;
    u16x8 o0, o1;
    #pragma unroll
    for(int i=0;i<8;++i)  o0[i] = tile[(sc*16 + i)*80 + d];
    #pragma unroll
    for(int i=0;i<8;++i)  o1[i] = tile[(sc*16 + 8 + i)*80 + d];
    u16* dst = Vt + ((size_t)(b*NH_ + h)*HD_ + d)*S_ + st*64 + sc*16;
    *(u16x8*)dst       = o0;
    *(u16x8*)(dst + 8) = o1;
  }
}

// ---------------- GEMM: C[M][N] = A[M][K](bf16) * Bt[N][K]^T + bias ----------------
// 128x128 tile, BK=32, 4 waves (2x2 of 64x64), double-buffered global_load_lds.
template<bool F32OUT>
__global__ __launch_bounds__(256,2) void gemm_kernel(const u16* __restrict__ A,
        const u16* __restrict__ Bt, const float* __restrict__ bias,
        void* __restrict__ Cout, int N, int K){
  __shared__ __attribute__((aligned(16))) u16 Al[2][128*32];
  __shared__ __attribute__((aligned(16))) u16 Bl[2][128*32];
  const int t = threadIdx.x, w = t >> 6, l = t & 63;
  const int c = l & 15, g = l >> 4;
  const int wm = w >> 1, wn = w & 1;
  const size_t mb = (size_t)blockIdx.x * 128;
  const size_t nb = (size_t)blockIdx.y * 128;

  auto stage = [&](int bb, int k0){
    #pragma unroll
    for(int j=0;j<2;++j){
      int row = 32*w + 16*j + (l >> 2);
      const u16* sa = A  + (mb + row)*K + k0 + (l & 3)*8;
      g2l16(sa, &Al[bb][(32*w + 16*j)*32]);
      const u16* sb = Bt + (nb + row)*K + k0 + (l & 3)*8;
      g2l16(sb, &Bl[bb][(32*w + 16*j)*32]);
    }
  };

  f32x4 acc[4][4];
  #pragma unroll
  for(int i=0;i<4;++i)
    #pragma unroll
    for(int j=0;j<4;++j) acc[i][j] = 0.f;

  stage(0, 0);
  __syncthreads();
  const int NK = K/32;
  for(int kt=0; kt<NK; ++kt){
    int bb = kt & 1;
    if(kt+1 < NK) stage(bb^1, (kt+1)*32);
    bf16x8 af[4], bfr[4];
    #pragma unroll
    for(int mf=0;mf<4;++mf)
      af[mf]  = *(const bf16x8*)&Al[bb][(64*wm + 16*mf + c)*32 + g*8];
    #pragma unroll
    for(int nf=0;nf<4;++nf)
      bfr[nf] = *(const bf16x8*)&Bl[bb][(64*wn + 16*nf + c)*32 + g*8];
    #pragma unroll
    for(int mf=0;mf<4;++mf)
      #pragma unroll
      for(int nf=0;nf<4;++nf)
        acc[mf][nf] = __builtin_amdgcn_mfma_f32_16x16x32_bf16(af[mf], bfr[nf], acc[mf][nf], 0,0,0);
    __syncthreads();
  }

  float bcol[4];
  #pragma unroll
  for(int nf=0;nf<4;++nf) bcol[nf] = bias[nb + 64*wn + 16*nf + c];
  #pragma unroll
  for(int mf=0;mf<4;++mf)
    #pragma unroll
    for(int nf=0;nf<4;++nf)
      #pragma unroll
      for(int r=0;r<4;++r){
        size_t row = mb + 64*wm + 16*mf + 4*g + r;
        size_t col = nb + 64*wn + 16*nf + c;
        float v = acc[mf][nf][r] + bcol[nf];
        if (F32OUT) ((float*)Cout)[row*N + col] = v;
        else        ((u16*)Cout)[row*N + col]   = f2bf(v);
      }
}

// ---------------- fused flash attention ----------------
// grid (S/64, NH, B), 256 thr = 4 waves, wave = 16 q-rows.
// Swapped QK^T: S^T = mfma(K, Q^T) -> lane owns q = l&15 entirely.
// K/V tiles (64x64 bf16) in XOR-swizzled LDS (chunk ^= row&7 on 128B rows).
__global__ __launch_bounds__(256,2) void attn_kernel(const u16* __restrict__ qkv,
        const u16* __restrict__ Vt, u16* __restrict__ ya){
  __shared__ __attribute__((aligned(16))) u16 Kl[2][64*64];
  __shared__ __attribute__((aligned(16))) u16 Vl[2][64*64];
  __shared__ __attribute__((aligned(16))) u16 Ol[4][16*80];
  const int qt = blockIdx.x, h = blockIdx.y, b = blockIdx.z;
  const int t = threadIdx.x, w = t >> 6, l = t & 63;
  const int c = l & 15, g = l >> 4;
  const int q0 = qt*64 + 16*w;

  // Q fragments (B operand of swapped QK^T): lane -> Q[q0+c][32*ks + 8*g .. +7]
  bf16x8 qf[2];
  {
    const u16* qp = qkv + (size_t)(b*S_ + q0 + c)*D3 + h*HD_ + g*8;
    qf[0] = *(const bf16x8*)qp;
    qf[1] = *(const bf16x8*)(qp + 32);
  }

  f32x4 o[4];
  #pragma unroll
  for(int i=0;i<4;++i) o[i] = 0.f;
  float mrun = -INFINITY, lsum = 0.f;

  auto stage = [&](int bb, int kt){
    if (w < 2){
      int rbase = 32*w;
      #pragma unroll
      for(int j=0;j<4;++j){
        int row = rbase + 8*j + (l >> 3);
        int ch  = (l & 7) ^ (row & 7);
        const u16* src = qkv + (size_t)(b*S_ + kt*64 + row)*D3 + D_ + h*HD_ + ch*8;
        g2l16(src, &Kl[bb][(rbase + 8*j)*64]);
      }
    } else {
      int rbase = 32*(w-2);
      #pragma unroll
      for(int j=0;j<4;++j){
        int row = rbase + 8*j + (l >> 3);          // row = d
        int ch  = (l & 7) ^ (row & 7);
        const u16* src = Vt + ((size_t)(b*NH_ + h)*HD_ + row)*S_ + kt*64 + ch*8;
        g2l16(src, &Vl[bb][(rbase + 8*j)*64]);
      }
    }
  };

  stage(0, 0);
  __syncthreads();

  for(int kt=0; kt<S_/64; ++kt){
    int bb = kt & 1;
    if (kt+1 < S_/64) stage(bb^1, kt+1);

    // --- S^T = K * Q^T : s[mf] covers kpos 16mf+4g+r for q=c ---
    f32x4 s[4];
    #pragma unroll
    for(int i=0;i<4;++i) s[i] = 0.f;
    #pragma unroll
    for(int ks=0; ks<2; ++ks)
      #pragma unroll
      for(int mf=0; mf<4; ++mf){
        int row = 16*mf + c;
        int sl  = (4*ks + g) ^ (row & 7);
        bf16x8 kf = *(const bf16x8*)&Kl[bb][row*64 + sl*8];
        s[mf] = __builtin_amdgcn_mfma_f32_16x16x32_bf16(kf, qf[ks], s[mf], 0,0,0);
      }

    // --- online softmax (raw-score max; scale folded into exp2) ---
    float tm = fmaxf(fmaxf(fmaxf(s[0][0],s[0][1]),fmaxf(s[0][2],s[0][3])),
              fmaxf(fmaxf(fmaxf(s[1][0],s[1][1]),fmaxf(s[1][2],s[1][3])),
              fmaxf(fmaxf(fmaxf(s[2][0],s[2][1]),fmaxf(s[2][2],s[2][3])),
                    fmaxf(fmaxf(s[3][0],s[3][1]),fmaxf(s[3][2],s[3][3])))));
    tm = fmaxf(tm, __shfl_xor(tm, 16));
    tm = fmaxf(tm, __shfl_xor(tm, 32));
    float mnew  = fmaxf(mrun, tm);
    float alpha = EXP2((mrun - mnew)*CSC);
    float mC    = mnew*CSC;
    float p[16]; float ps = 0.f;
    #pragma unroll
    for(int mf=0;mf<4;++mf)
      #pragma unroll
      for(int r=0;r<4;++r){
        float pv = EXP2(__builtin_fmaf(s[mf][r], CSC, -mC));
        p[mf*4+r] = pv; ps += pv;
      }
    ps += __shfl_xor(ps, 16);
    ps += __shfl_xor(ps, 32);
    lsum = lsum*alpha + ps;
    mrun = mnew;
    #pragma unroll
    for(int mf=0;mf<4;++mf) o[mf] *= alpha;

    // --- pack P to bf16 pairs: pk[mf*2+j] = (r=2j, r=2j+1) ---
    u32 pk[8];
    #pragma unroll
    for(int mf=0;mf<4;++mf){
      pk[mf*2+0] = cvtpk(p[mf*4+0], p[mf*4+1]);
      pk[mf*2+1] = cvtpk(p[mf*4+2], p[mf*4+3]);
    }

    // --- PV: O^T += V^T * P^T ; B-frag gathered via ds_bpermute ---
    int aA = ((c + 32*(g & 1)) << 2);
    int aB = aA + 64;
    bool hi = (g >= 2);
    #pragma unroll
    for(int t2=0; t2<2; ++t2){
      u32 b0a = __builtin_amdgcn_ds_bpermute(aA, (int)pk[4*t2 + 0]);
      u32 b0b = __builtin_amdgcn_ds_bpermute(aA, (int)pk[4*t2 + 2]);
      u32 b1a = __builtin_amdgcn_ds_bpermute(aA, (int)pk[4*t2 + 1]);
      u32 b1b = __builtin_amdgcn_ds_bpermute(aA, (int)pk[4*t2 + 3]);
      u32 b2a = __builtin_amdgcn_ds_bpermute(aB, (int)pk[4*t2 + 0]);
      u32 b2b = __builtin_amdgcn_ds_bpermute(aB, (int)pk[4*t2 + 2]);
      u32 b3a = __builtin_amdgcn_ds_bpermute(aB, (int)pk[4*t2 + 1]);
      u32 b3b = __builtin_amdgcn_ds_bpermute(aB, (int)pk[4*t2 + 3]);
      i32x4 bi;
      bi[0] = (int)(hi ? b0b : b0a);
      bi[1] = (int)(hi ? b1b : b1a);
      bi[2] = (int)(hi ? b2b : b2a);
      bi[3] = (int)(hi ? b3b : b3a);
      bf16x8 pf = __builtin_bit_cast(bf16x8, bi);
      #pragma unroll
      for(int mf=0; mf<4; ++mf){
        int row = 16*mf + c;                 // row = d
        int sl  = (4*t2 + g) ^ (row & 7);
        bf16x8 vf = *(const bf16x8*)&Vl[bb][row*64 + sl*8];
        o[mf] = __builtin_amdgcn_mfma_f32_16x16x32_bf16(vf, pf, o[mf], 0,0,0);
      }
    }
    __syncthreads();
  }

  // --- epilogue: O^T regs (all q=c) -> LDS -> coalesced bf16 store ---
  float inv = 1.f / lsum;
  #pragma unroll
  for(int mf=0;mf<4;++mf)
    #pragma unroll
    for(int r=0;r<4;++r){
      int d = 16*mf + 4*g + r;
      Ol[w][c*80 + d] = f2bf(o[mf][r]*inv);
    }
  __syncthreads();
  {
    int q = l >> 2, dc = l & 3;
    u16x8 o0 = *(u16x8*)&Ol[w][q*80 + dc*16];
    u16x8 o1 = *(u16x8*)&Ol[w][q*80 + dc*16 + 8];
    u16* dst = ya + (size_t)(b*S_ + q0 + q)*D_ + h*HD_ + dc*16;
    *(u16x8*)dst       = o0;
    *(u16x8*)(dst + 8) = o1;
  }
}

extern "C" void kernel_launch(void* const* d_in, const int* in_sizes, int n_in,
                              void* d_out, int out_size, void* d_ws, size_t ws_size,
                              hipStream_t stream){
  const float* x      = (const float*)d_in[0];
  const float* w_attn = (const float*)d_in[1];
  const float* b_attn = (const float*)d_in[2];
  const float* w_proj = (const float*)d_in[3];
  const float* b_proj = (const float*)d_in[4];
  float* out = (float*)d_out;

  char* ws = (char*)d_ws;
  u16* xb  = (u16*)ws;  ws += (size_t)TOK*D_*2;   // 16.8 MB
  u16* waT = (u16*)ws;  ws += (size_t)D3*D_*2;    //  6.3 MB
  u16* wpT = (u16*)ws;  ws += (size_t)D_*D_*2;    //  2.1 MB
  u16* qkv = (u16*)ws;  ws += (size_t)TOK*D3*2;   // 50.3 MB
  u16* Vt  = (u16*)ws;  ws += (size_t)TOK*D_*2;   // 16.8 MB
  u16* ya  = (u16*)ws;  ws += (size_t)TOK*D_*2;   // 16.8 MB  (total ~109 MB)

  castx_kernel<<<TOK*D_/(256*8), 256, 0, stream>>>(x, xb);
  tcast_kernel<<<dim3(D_/32, D3/32), 256, 0, stream>>>(w_attn, waT, D_, D3);
  tcast_kernel<<<dim3(D_/32, D_/32), 256, 0, stream>>>(w_proj, wpT, D_, D_);
  gemm_kernel<false><<<dim3(TOK/128, D3/128), 256, 0, stream>>>(xb, waT, b_attn, qkv, D3, D_);
  vtrans_kernel<<<dim3(S_/64, NH_, B_), 256, 0, stream>>>(qkv, Vt);
  attn_kernel<<<dim3(S_/64, NH_, B_), 256, 0, stream>>>(qkv, Vt, ya);
  gemm_kernel<true><<<dim3(TOK/128, D_/128), 256, 0, stream>>>(ya, wpT, b_proj, out, D_, D_);
}

// Round 9
// 330.066 us; speedup vs baseline: 1.0392x; 1.0392x over previous
//
#include <hip/hip_runtime.h>
#include <stdint.h>

#define B_   4
#define S_   2048
#define D_   1024
#define NH_  16
#define HD_  64
#define D3   (3*D_)
#define TOK  (B_*S_)

typedef unsigned short u16;
typedef unsigned int   u32;
typedef float    f32x4  __attribute__((ext_vector_type(4)));
typedef __bf16   bf16x8 __attribute__((ext_vector_type(8)));
typedef u16      u16x8  __attribute__((ext_vector_type(8)));
typedef int      i32x4  __attribute__((ext_vector_type(4)));

#if __has_builtin(__builtin_amdgcn_exp2f)
#define EXP2(x) __builtin_amdgcn_exp2f(x)
#else
#define EXP2(x) exp2f(x)
#endif

// 0.125 (1/sqrt(64)) * log2(e): softmax on scaled logits via exp2
#define CSC 0.18033688011112042f

__device__ __forceinline__ u16 f2bf(float f){
  u32 x = __float_as_uint(f);
  x += 0x7fffu + ((x >> 16) & 1u);   // RNE; inputs are well-behaved (no NaN)
  return (u16)(x >> 16);
}

__device__ __forceinline__ u32 cvtpk(float lo, float hi){
  u32 r;
  asm("v_cvt_pk_bf16_f32 %0, %1, %2" : "=v"(r) : "v"(lo), "v"(hi));
  return r;
}

__device__ __forceinline__ void g2l16(const u16* g, u16* l){
  __builtin_amdgcn_global_load_lds((const __attribute__((address_space(1))) u32*)(g),
                                   (__attribute__((address_space(3))) u32*)(l), 16, 0, 0);
}

// ---------------- cast x (f32 -> bf16), 8 elems/thread ----------------
__global__ __launch_bounds__(256) void castx_kernel(const float* __restrict__ in,
                                                    u16* __restrict__ out){
  size_t i = ((size_t)blockIdx.x*256 + threadIdx.x)*8;
  f32x4 a = *(const f32x4*)(in + i);
  f32x4 b = *(const f32x4*)(in + i + 4);
  i32x4 v;
  v[0] = cvtpk(a[0], a[1]); v[1] = cvtpk(a[2], a[3]);
  v[2] = cvtpk(b[0], b[1]); v[3] = cvtpk(b[2], b[3]);
  *(i32x4*)(out + i) = v;
}

// ------------- transpose-cast W[K][N] f32 -> Wt[N][K] bf16 -------------
__global__ __launch_bounds__(256) void tcast_kernel(const float* __restrict__ in,
                                                    u16* __restrict__ out, int K, int N){
  __shared__ float tile[32][33];
  int i0 = blockIdx.x*32;          // K dim
  int j0 = blockIdx.y*32;          // N dim
  int t  = threadIdx.x;
  int cl = t & 31, rq = t >> 5;
  #pragma unroll
  for(int it=0; it<4; ++it){
    int r = rq + it*8;
    tile[r][cl] = in[(size_t)(i0 + r)*N + j0 + cl];
  }
  __syncthreads();
  #pragma unroll
  for(int it=0; it<4; ++it){
    int r = rq + it*8;             // n-local
    out[(size_t)(j0 + r)*K + i0 + cl] = f2bf(tile[cl][r]);
  }
}

// ------------- V transpose: qkv V-block -> Vt[b][h][d][s] bf16 -------------
__global__ __launch_bounds__(256) void vtrans_kernel(const u16* __restrict__ qkv,
                                                     u16* __restrict__ Vt){
  __shared__ __attribute__((aligned(16))) u16 tile[64*80];  // pad to 80 for alignment
  int st = blockIdx.x, h = blockIdx.y, b = blockIdx.z;
  int t = threadIdx.x;
  {
    int s = t >> 2, dc = t & 3;
    const u16* src = qkv + (size_t)(b*S_ + st*64 + s)*D3 + 2*D_ + h*HD_ + dc*16;
    *(u16x8*)&tile[s*80 + dc*16]     = *(const u16x8*)src;
    *(u16x8*)&tile[s*80 + dc*16 + 8] = *(const u16x8*)(src + 8);
  }
  __syncthreads();
  {
    int d = t >> 2, sc = t & 3;
    u16x8 o0, o1;
    #pragma unroll
    for(int i=0;i<8;++i)  o0[i] = tile[(sc*16 + i)*80 + d];
    #pragma unroll
    for(int i=0;i<8;++i)  o1[i] = tile[(sc*16 + 8 + i)*80 + d];
    u16* dst = Vt + ((size_t)(b*NH_ + h)*HD_ + d)*S_ + st*64 + sc*16;
    *(u16x8*)dst       = o0;
    *(u16x8*)(dst + 8) = o1;
  }
}

// ---------------- GEMM: C[M][N] = A[M][K](bf16) * Bt[N][K]^T + bias ----------------
// 128x128 tile, BK=32, 4 waves (2x2 of 64x64), double-buffered global_load_lds.
template<bool F32OUT>
__global__ __launch_bounds__(256,2) void gemm_kernel(const u16* __restrict__ A,
        const u16* __restrict__ Bt, const float* __restrict__ bias,
        void* __restrict__ Cout, int N, int K){
  __shared__ __attribute__((aligned(16))) u16 Al[2][128*32];
  __shared__ __attribute__((aligned(16))) u16 Bl[2][128*32];
  const int t = threadIdx.x, w = t >> 6, l = t & 63;
  const int c = l & 15, g = l >> 4;
  const int wm = w >> 1, wn = w & 1;
  const size_t mb = (size_t)blockIdx.x * 128;
  const size_t nb = (size_t)blockIdx.y * 128;

  auto stage = [&](int bb, int k0){
    #pragma unroll
    for(int j=0;j<2;++j){
      int row = 32*w + 16*j + (l >> 2);
      const u16* sa = A  + (mb + row)*K + k0 + (l & 3)*8;
      g2l16(sa, &Al[bb][(32*w + 16*j)*32]);
      const u16* sb = Bt + (nb + row)*K + k0 + (l & 3)*8;
      g2l16(sb, &Bl[bb][(32*w + 16*j)*32]);
    }
  };

  f32x4 acc[4][4];
  #pragma unroll
  for(int i=0;i<4;++i)
    #pragma unroll
    for(int j=0;j<4;++j) acc[i][j] = 0.f;

  stage(0, 0);
  __syncthreads();
  const int NK = K/32;
  for(int kt=0; kt<NK; ++kt){
    int bb = kt & 1;
    if(kt+1 < NK) stage(bb^1, (kt+1)*32);
    bf16x8 af[4], bfr[4];
    #pragma unroll
    for(int mf=0;mf<4;++mf)
      af[mf]  = *(const bf16x8*)&Al[bb][(64*wm + 16*mf + c)*32 + g*8];
    #pragma unroll
    for(int nf=0;nf<4;++nf)
      bfr[nf] = *(const bf16x8*)&Bl[bb][(64*wn + 16*nf + c)*32 + g*8];
    __builtin_amdgcn_s_setprio(1);
    #pragma unroll
    for(int mf=0;mf<4;++mf)
      #pragma unroll
      for(int nf=0;nf<4;++nf)
        acc[mf][nf] = __builtin_amdgcn_mfma_f32_16x16x32_bf16(af[mf], bfr[nf], acc[mf][nf], 0,0,0);
    __builtin_amdgcn_s_setprio(0);
    __syncthreads();
  }

  float bcol[4];
  #pragma unroll
  for(int nf=0;nf<4;++nf) bcol[nf] = bias[nb + 64*wn + 16*nf + c];
  #pragma unroll
  for(int mf=0;mf<4;++mf)
    #pragma unroll
    for(int nf=0;nf<4;++nf)
      #pragma unroll
      for(int r=0;r<4;++r){
        size_t row = mb + 64*wm + 16*mf + 4*g + r;
        size_t col = nb + 64*wn + 16*nf + c;
        float v = acc[mf][nf][r] + bcol[nf];
        if (F32OUT) ((float*)Cout)[row*N + col] = v;
        else        ((u16*)Cout)[row*N + col]   = f2bf(v);
      }
}

// ---------------- fused flash attention ----------------
// grid (S/64, NH, B), 256 thr = 4 waves, wave = 16 q-rows.
// Swapped QK^T: S^T = mfma(K, Q^T) -> lane owns q = l&15 entirely.
// K/V tiles (64x64 bf16) in XOR-swizzled LDS (chunk ^= row&7 on 128B rows).
// LDS: K,V double-buffers = 32KB; epilogue O-tile UNIONed over K buffer
// -> 5 blocks/CU (was ~2.4 at 43KB).
// Softmax math = round-1 exactly (unconditional rescale, per-tile ps reduce):
// bisection round — only the union + setprio vs the passing baseline.
__global__ __launch_bounds__(256,2) void attn_kernel(const u16* __restrict__ qkv,
        const u16* __restrict__ Vt, u16* __restrict__ ya){
  __shared__ __attribute__((aligned(16))) char smem_raw[32768];
  u16* Kl = (u16*)smem_raw;                 // [2][64*64]
  u16* Vl = (u16*)(smem_raw + 16384);       // [2][64*64]
  u16* Ol = (u16*)smem_raw;                 // [4][16*80], epilogue only
  const int qt = blockIdx.x, h = blockIdx.y, b = blockIdx.z;
  const int t = threadIdx.x, w = t >> 6, l = t & 63;
  const int c = l & 15, g = l >> 4;
  const int q0 = qt*64 + 16*w;

  // Q fragments (B operand of swapped QK^T): lane -> Q[q0+c][32*ks + 8*g .. +7]
  bf16x8 qf[2];
  {
    const u16* qp = qkv + (size_t)(b*S_ + q0 + c)*D3 + h*HD_ + g*8;
    qf[0] = *(const bf16x8*)qp;
    qf[1] = *(const bf16x8*)(qp + 32);
  }

  f32x4 o[4];
  #pragma unroll
  for(int i=0;i<4;++i) o[i] = 0.f;
  float mrun = -INFINITY, lsum = 0.f;

  auto stage = [&](int bb, int kt){
    if (w < 2){
      int rbase = 32*w;
      #pragma unroll
      for(int j=0;j<4;++j){
        int row = rbase + 8*j + (l >> 3);
        int ch  = (l & 7) ^ (row & 7);
        const u16* src = qkv + (size_t)(b*S_ + kt*64 + row)*D3 + D_ + h*HD_ + ch*8;
        g2l16(src, Kl + bb*4096 + (rbase + 8*j)*64);
      }
    } else {
      int rbase = 32*(w-2);
      #pragma unroll
      for(int j=0;j<4;++j){
        int row = rbase + 8*j + (l >> 3);          // row = d
        int ch  = (l & 7) ^ (row & 7);
        const u16* src = Vt + ((size_t)(b*NH_ + h)*HD_ + row)*S_ + kt*64 + ch*8;
        g2l16(src, Vl + bb*4096 + (rbase + 8*j)*64);
      }
    }
  };

  stage(0, 0);
  __syncthreads();

  for(int kt=0; kt<S_/64; ++kt){
    int bb = kt & 1;
    if (kt+1 < S_/64) stage(bb^1, kt+1);

    // --- S^T = K * Q^T : s[mf] covers kpos 16mf+4g+r for q=c ---
    f32x4 s[4];
    #pragma unroll
    for(int i=0;i<4;++i) s[i] = 0.f;
    __builtin_amdgcn_s_setprio(1);
    #pragma unroll
    for(int ks=0; ks<2; ++ks)
      #pragma unroll
      for(int mf=0; mf<4; ++mf){
        int row = 16*mf + c;
        int sl  = (4*ks + g) ^ (row & 7);
        bf16x8 kf = *(const bf16x8*)&Kl[bb*4096 + row*64 + sl*8];
        s[mf] = __builtin_amdgcn_mfma_f32_16x16x32_bf16(kf, qf[ks], s[mf], 0,0,0);
      }
    __builtin_amdgcn_s_setprio(0);

    // --- online softmax (round-1 math: unconditional rescale) ---
    float tm = fmaxf(fmaxf(fmaxf(s[0][0],s[0][1]),fmaxf(s[0][2],s[0][3])),
              fmaxf(fmaxf(fmaxf(s[1][0],s[1][1]),fmaxf(s[1][2],s[1][3])),
              fmaxf(fmaxf(fmaxf(s[2][0],s[2][1]),fmaxf(s[2][2],s[2][3])),
                    fmaxf(fmaxf(s[3][0],s[3][1]),fmaxf(s[3][2],s[3][3])))));
    tm = fmaxf(tm, __shfl_xor(tm, 16));
    tm = fmaxf(tm, __shfl_xor(tm, 32));
    float mnew  = fmaxf(mrun, tm);
    float alpha = EXP2((mrun - mnew)*CSC);
    float mC    = mnew*CSC;
    float p[16]; float ps = 0.f;
    #pragma unroll
    for(int mf=0;mf<4;++mf)
      #pragma unroll
      for(int r=0;r<4;++r){
        float pv = EXP2(__builtin_fmaf(s[mf][r], CSC, -mC));
        p[mf*4+r] = pv; ps += pv;
      }
    ps += __shfl_xor(ps, 16);
    ps += __shfl_xor(ps, 32);
    lsum = lsum*alpha + ps;
    mrun = mnew;
    #pragma unroll
    for(int mf=0;mf<4;++mf) o[mf] *= alpha;

    // --- pack P to bf16 pairs: pk[mf*2+j] = (r=2j, r=2j+1) ---
    u32 pk[8];
    #pragma unroll
    for(int mf=0;mf<4;++mf){
      pk[mf*2+0] = cvtpk(p[mf*4+0], p[mf*4+1]);
      pk[mf*2+1] = cvtpk(p[mf*4+2], p[mf*4+3]);
    }

    // --- PV: O^T += V^T * P^T ; B-frag gathered via ds_bpermute ---
    int aA = ((c + 32*(g & 1)) << 2);
    int aB = aA + 64;
    bool hi = (g >= 2);
    #pragma unroll
    for(int t2=0; t2<2; ++t2){
      u32 b0a = __builtin_amdgcn_ds_bpermute(aA, (int)pk[4*t2 + 0]);
      u32 b0b = __builtin_amdgcn_ds_bpermute(aA, (int)pk[4*t2 + 2]);
      u32 b1a = __builtin_amdgcn_ds_bpermute(aA, (int)pk[4*t2 + 1]);
      u32 b1b = __builtin_amdgcn_ds_bpermute(aA, (int)pk[4*t2 + 3]);
      u32 b2a = __builtin_amdgcn_ds_bpermute(aB, (int)pk[4*t2 + 0]);
      u32 b2b = __builtin_amdgcn_ds_bpermute(aB, (int)pk[4*t2 + 2]);
      u32 b3a = __builtin_amdgcn_ds_bpermute(aB, (int)pk[4*t2 + 1]);
      u32 b3b = __builtin_amdgcn_ds_bpermute(aB, (int)pk[4*t2 + 3]);
      i32x4 bi;
      bi[0] = (int)(hi ? b0b : b0a);
      bi[1] = (int)(hi ? b1b : b1a);
      bi[2] = (int)(hi ? b2b : b2a);
      bi[3] = (int)(hi ? b3b : b3a);
      bf16x8 pf = __builtin_bit_cast(bf16x8, bi);
      __builtin_amdgcn_s_setprio(1);
      #pragma unroll
      for(int mf=0; mf<4; ++mf){
        int row = 16*mf + c;                 // row = d
        int sl  = (4*t2 + g) ^ (row & 7);
        bf16x8 vf = *(const bf16x8*)&Vl[bb*4096 + row*64 + sl*8];
        o[mf] = __builtin_amdgcn_mfma_f32_16x16x32_bf16(vf, pf, o[mf], 0,0,0);
      }
      __builtin_amdgcn_s_setprio(0);
    }
    __syncthreads();
  }

  // --- epilogue: O^T regs (all q=c) -> LDS -> coalesced bf16 store ---
  float inv = 1.f / lsum;
  __syncthreads();   // belt-and-braces before writing the unioned Ol region
  #pragma unroll
  for(int mf=0;mf<4;++mf)
    #pragma unroll
    for(int r=0;r<4;++r){
      int d = 16*mf + 4*g + r;
      Ol[w*1280 + c*80 + d] = f2bf(o[mf][r]*inv);
    }
  __syncthreads();
  {
    int q = l >> 2, dc = l & 3;
    u16x8 o0 = *(u16x8*)&Ol[w*1280 + q*80 + dc*16];
    u16x8 o1 = *(u16x8*)&Ol[w*1280 + q*80 + dc*16 + 8];
    u16* dst = ya + (size_t)(b*S_ + q0 + q)*D_ + h*HD_ + dc*16;
    *(u16x8*)dst       = o0;
    *(u16x8*)(dst + 8) = o1;
  }
}

extern "C" void kernel_launch(void* const* d_in, const int* in_sizes, int n_in,
                              void* d_out, int out_size, void* d_ws, size_t ws_size,
                              hipStream_t stream){
  const float* x      = (const float*)d_in[0];
  const float* w_attn = (const float*)d_in[1];
  const float* b_attn = (const float*)d_in[2];
  const float* w_proj = (const float*)d_in[3];
  const float* b_proj = (const float*)d_in[4];
  float* out = (float*)d_out;

  char* ws = (char*)d_ws;
  u16* xb  = (u16*)ws;  ws += (size_t)TOK*D_*2;   // 16.8 MB
  u16* waT = (u16*)ws;  ws += (size_t)D3*D_*2;    //  6.3 MB
  u16* wpT = (u16*)ws;  ws += (size_t)D_*D_*2;    //  2.1 MB
  u16* qkv = (u16*)ws;  ws += (size_t)TOK*D3*2;   // 50.3 MB
  u16* Vt  = (u16*)ws;  ws += (size_t)TOK*D_*2;   // 16.8 MB
  u16* ya  = (u16*)ws;  ws += (size_t)TOK*D_*2;   // 16.8 MB  (total ~109 MB)

  castx_kernel<<<TOK*D_/(256*8), 256, 0, stream>>>(x, xb);
  tcast_kernel<<<dim3(D_/32, D3/32), 256, 0, stream>>>(w_attn, waT, D_, D3);
  tcast_kernel<<<dim3(D_/32, D_/32), 256, 0, stream>>>(w_proj, wpT, D_, D_);
  gemm_kernel<false><<<dim3(TOK/128, D3/128), 256, 0, stream>>>(xb, waT, b_attn, qkv, D3, D_);
  vtrans_kernel<<<dim3(S_/64, NH_, B_), 256, 0, stream>>>(qkv, Vt);
  attn_kernel<<<dim3(S_/64, NH_, B_), 256, 0, stream>>>(qkv, Vt, ya);
  gemm_kernel<true><<<dim3(TOK/128, D_/128), 256, 0, stream>>>(ya, wpT, b_proj, out, D_, D_);
}

// Round 10
// 318.219 us; speedup vs baseline: 1.0779x; 1.0372x over previous
//
#include <hip/hip_runtime.h>
#include <stdint.h>

#define B_   4
#define S_   2048
#define D_   1024
#define NH_  16
#define HD_  64
#define D3   (3*D_)
#define TOK  (B_*S_)

typedef unsigned short u16;
typedef unsigned int   u32;
typedef float    f32x4  __attribute__((ext_vector_type(4)));
typedef __bf16   bf16x8 __attribute__((ext_vector_type(8)));
typedef u16      u16x8  __attribute__((ext_vector_type(8)));
typedef int      i32x4  __attribute__((ext_vector_type(4)));

#if __has_builtin(__builtin_amdgcn_exp2f)
#define EXP2(x) __builtin_amdgcn_exp2f(x)
#else
#define EXP2(x) exp2f(x)
#endif

// 0.125 (1/sqrt(64)) * log2(e): softmax on scaled logits via exp2
#define CSC 0.18033688011112042f

__device__ __forceinline__ u16 f2bf(float f){
  u32 x = __float_as_uint(f);
  x += 0x7fffu + ((x >> 16) & 1u);   // RNE; inputs are well-behaved (no NaN)
  return (u16)(x >> 16);
}

__device__ __forceinline__ u32 cvtpk(float lo, float hi){
  u32 r;
  asm("v_cvt_pk_bf16_f32 %0, %1, %2" : "=v"(r) : "v"(lo), "v"(hi));
  return r;
}

__device__ __forceinline__ void g2l16(const u16* g, u16* l){
  __builtin_amdgcn_global_load_lds((const __attribute__((address_space(1))) u32*)(g),
                                   (__attribute__((address_space(3))) u32*)(l), 16, 0, 0);
}

// ---------------- cast x (f32 -> bf16), 8 elems/thread ----------------
__global__ __launch_bounds__(256) void castx_kernel(const float* __restrict__ in,
                                                    u16* __restrict__ out){
  size_t i = ((size_t)blockIdx.x*256 + threadIdx.x)*8;
  f32x4 a = *(const f32x4*)(in + i);
  f32x4 b = *(const f32x4*)(in + i + 4);
  i32x4 v;
  v[0] = cvtpk(a[0], a[1]); v[1] = cvtpk(a[2], a[3]);
  v[2] = cvtpk(b[0], b[1]); v[3] = cvtpk(b[2], b[3]);
  *(i32x4*)(out + i) = v;
}

// ------------- transpose-cast W[K][N] f32 -> Wt[N][K] bf16 -------------
__global__ __launch_bounds__(256) void tcast_kernel(const float* __restrict__ in,
                                                    u16* __restrict__ out, int K, int N){
  __shared__ float tile[32][33];
  int i0 = blockIdx.x*32;          // K dim
  int j0 = blockIdx.y*32;          // N dim
  int t  = threadIdx.x;
  int cl = t & 31, rq = t >> 5;
  #pragma unroll
  for(int it=0; it<4; ++it){
    int r = rq + it*8;
    tile[r][cl] = in[(size_t)(i0 + r)*N + j0 + cl];
  }
  __syncthreads();
  #pragma unroll
  for(int it=0; it<4; ++it){
    int r = rq + it*8;             // n-local
    out[(size_t)(j0 + r)*K + i0 + cl] = f2bf(tile[cl][r]);
  }
}

// ------------- V transpose: qkv V-block -> Vt[b][h][d][s] bf16 -------------
__global__ __launch_bounds__(256) void vtrans_kernel(const u16* __restrict__ qkv,
                                                     u16* __restrict__ Vt){
  __shared__ __attribute__((aligned(16))) u16 tile[64*80];  // pad to 80 for alignment
  int st = blockIdx.x, h = blockIdx.y, b = blockIdx.z;
  int t = threadIdx.x;
  {
    int s = t >> 2, dc = t & 3;
    const u16* src = qkv + (size_t)(b*S_ + st*64 + s)*D3 + 2*D_ + h*HD_ + dc*16;
    *(u16x8*)&tile[s*80 + dc*16]     = *(const u16x8*)src;
    *(u16x8*)&tile[s*80 + dc*16 + 8] = *(const u16x8*)(src + 8);
  }
  __syncthreads();
  {
    int d = t >> 2, sc = t & 3;
    u16x8 o0, o1;
    #pragma unroll
    for(int i=0;i<8;++i)  o0[i] = tile[(sc*16 + i)*80 + d];
    #pragma unroll
    for(int i=0;i<8;++i)  o1[i] = tile[(sc*16 + 8 + i)*80 + d];
    u16* dst = Vt + ((size_t)(b*NH_ + h)*HD_ + d)*S_ + st*64 + sc*16;
    *(u16x8*)dst       = o0;
    *(u16x8*)(dst + 8) = o1;
  }
}

// ---------------- GEMM: C[M][N] = A[M][K](bf16) * Bt[N][K]^T + bias ----------------
// 128x128 tile, BK=32, 4 waves (2x2 of 64x64), double-buffered global_load_lds.
template<bool F32OUT>
__global__ __launch_bounds__(256,2) void gemm_kernel(const u16* __restrict__ A,
        const u16* __restrict__ Bt, const float* __restrict__ bias,
        void* __restrict__ Cout, int N, int K){
  __shared__ __attribute__((aligned(16))) u16 Al[2][128*32];
  __shared__ __attribute__((aligned(16))) u16 Bl[2][128*32];
  const int t = threadIdx.x, w = t >> 6, l = t & 63;
  const int c = l & 15, g = l >> 4;
  const int wm = w >> 1, wn = w & 1;
  const size_t mb = (size_t)blockIdx.x * 128;
  const size_t nb = (size_t)blockIdx.y * 128;

  auto stage = [&](int bb, int k0){
    #pragma unroll
    for(int j=0;j<2;++j){
      int row = 32*w + 16*j + (l >> 2);
      const u16* sa = A  + (mb + row)*K + k0 + (l & 3)*8;
      g2l16(sa, &Al[bb][(32*w + 16*j)*32]);
      const u16* sb = Bt + (nb + row)*K + k0 + (l & 3)*8;
      g2l16(sb, &Bl[bb][(32*w + 16*j)*32]);
    }
  };

  f32x4 acc[4][4];
  #pragma unroll
  for(int i=0;i<4;++i)
    #pragma unroll
    for(int j=0;j<4;++j) acc[i][j] = 0.f;

  stage(0, 0);
  __syncthreads();
  const int NK = K/32;
  for(int kt=0; kt<NK; ++kt){
    int bb = kt & 1;
    if(kt+1 < NK) stage(bb^1, (kt+1)*32);
    bf16x8 af[4], bfr[4];
    #pragma unroll
    for(int mf=0;mf<4;++mf)
      af[mf]  = *(const bf16x8*)&Al[bb][(64*wm + 16*mf + c)*32 + g*8];
    #pragma unroll
    for(int nf=0;nf<4;++nf)
      bfr[nf] = *(const bf16x8*)&Bl[bb][(64*wn + 16*nf + c)*32 + g*8];
    __builtin_amdgcn_s_setprio(1);
    #pragma unroll
    for(int mf=0;mf<4;++mf)
      #pragma unroll
      for(int nf=0;nf<4;++nf)
        acc[mf][nf] = __builtin_amdgcn_mfma_f32_16x16x32_bf16(af[mf], bfr[nf], acc[mf][nf], 0,0,0);
    __builtin_amdgcn_s_setprio(0);
    __syncthreads();
  }

  float bcol[4];
  #pragma unroll
  for(int nf=0;nf<4;++nf) bcol[nf] = bias[nb + 64*wn + 16*nf + c];
  #pragma unroll
  for(int mf=0;mf<4;++mf)
    #pragma unroll
    for(int nf=0;nf<4;++nf)
      #pragma unroll
      for(int r=0;r<4;++r){
        size_t row = mb + 64*wm + 16*mf + 4*g + r;
        size_t col = nb + 64*wn + 16*nf + c;
        float v = acc[mf][nf][r] + bcol[nf];
        if (F32OUT) ((float*)Cout)[row*N + col] = v;
        else        ((u16*)Cout)[row*N + col]   = f2bf(v);
      }
}

// ---------------- fused flash attention ----------------
// grid (S/128, NH, B), 512 thr = 8 waves, wave = 16 q-rows (block = 128 q-rows).
// Two Q-tiles share one K/V LDS double-buffer: same 32KB LDS, 2x waves per
// barrier-group -> up to 32 waves/CU (was ~12.6), K/V HBM re-reads halved.
// Per-wave math identical to round-9 passing kernel (round-1 softmax).
// Swapped QK^T: S^T = mfma(K, Q^T) -> lane owns q = l&15 entirely.
// K/V tiles (64x64 bf16) in XOR-swizzled LDS (chunk ^= row&7 on 128B rows).
// Epilogue O-tile [8][16*80] (20KB) UNIONed over K buffer.
__global__ __launch_bounds__(512,2) void attn_kernel(const u16* __restrict__ qkv,
        const u16* __restrict__ Vt, u16* __restrict__ ya){
  __shared__ __attribute__((aligned(16))) char smem_raw[32768];
  u16* Kl = (u16*)smem_raw;                 // [2][64*64]
  u16* Vl = (u16*)(smem_raw + 16384);       // [2][64*64]
  u16* Ol = (u16*)smem_raw;                 // [8][16*80], epilogue only
  const int qt = blockIdx.x, h = blockIdx.y, b = blockIdx.z;
  const int t = threadIdx.x, w = t >> 6, l = t & 63;
  const int c = l & 15, g = l >> 4;
  const int q0 = qt*128 + 16*w;

  // Q fragments (B operand of swapped QK^T): lane -> Q[q0+c][32*ks + 8*g .. +7]
  bf16x8 qf[2];
  {
    const u16* qp = qkv + (size_t)(b*S_ + q0 + c)*D3 + h*HD_ + g*8;
    qf[0] = *(const bf16x8*)qp;
    qf[1] = *(const bf16x8*)(qp + 32);
  }

  f32x4 o[4];
  #pragma unroll
  for(int i=0;i<4;++i) o[i] = 0.f;
  float mrun = -INFINITY, lsum = 0.f;

  auto stage = [&](int bb, int kt){
    if (w < 4){                         // waves 0-3: K tile, 16 rows each
      int rbase = 16*w;
      #pragma unroll
      for(int j=0;j<2;++j){
        int row = rbase + 8*j + (l >> 3);
        int ch  = (l & 7) ^ (row & 7);
        const u16* src = qkv + (size_t)(b*S_ + kt*64 + row)*D3 + D_ + h*HD_ + ch*8;
        g2l16(src, Kl + bb*4096 + (rbase + 8*j)*64);
      }
    } else {                            // waves 4-7: V tile (row = d), 16 rows each
      int rbase = 16*(w-4);
      #pragma unroll
      for(int j=0;j<2;++j){
        int row = rbase + 8*j + (l >> 3);
        int ch  = (l & 7) ^ (row & 7);
        const u16* src = Vt + ((size_t)(b*NH_ + h)*HD_ + row)*S_ + kt*64 + ch*8;
        g2l16(src, Vl + bb*4096 + (rbase + 8*j)*64);
      }
    }
  };

  stage(0, 0);
  __syncthreads();

  for(int kt=0; kt<S_/64; ++kt){
    int bb = kt & 1;
    if (kt+1 < S_/64) stage(bb^1, kt+1);

    // --- S^T = K * Q^T : s[mf] covers kpos 16mf+4g+r for q=c ---
    f32x4 s[4];
    #pragma unroll
    for(int i=0;i<4;++i) s[i] = 0.f;
    __builtin_amdgcn_s_setprio(1);
    #pragma unroll
    for(int ks=0; ks<2; ++ks)
      #pragma unroll
      for(int mf=0; mf<4; ++mf){
        int row = 16*mf + c;
        int sl  = (4*ks + g) ^ (row & 7);
        bf16x8 kf = *(const bf16x8*)&Kl[bb*4096 + row*64 + sl*8];
        s[mf] = __builtin_amdgcn_mfma_f32_16x16x32_bf16(kf, qf[ks], s[mf], 0,0,0);
      }
    __builtin_amdgcn_s_setprio(0);

    // --- online softmax (round-1 math: unconditional rescale) ---
    float tm = fmaxf(fmaxf(fmaxf(s[0][0],s[0][1]),fmaxf(s[0][2],s[0][3])),
              fmaxf(fmaxf(fmaxf(s[1][0],s[1][1]),fmaxf(s[1][2],s[1][3])),
              fmaxf(fmaxf(fmaxf(s[2][0],s[2][1]),fmaxf(s[2][2],s[2][3])),
                    fmaxf(fmaxf(s[3][0],s[3][1]),fmaxf(s[3][2],s[3][3])))));
    tm = fmaxf(tm, __shfl_xor(tm, 16));
    tm = fmaxf(tm, __shfl_xor(tm, 32));
    float mnew  = fmaxf(mrun, tm);
    float alpha = EXP2((mrun - mnew)*CSC);
    float mC    = mnew*CSC;
    float p[16]; float ps = 0.f;
    #pragma unroll
    for(int mf=0;mf<4;++mf)
      #pragma unroll
      for(int r=0;r<4;++r){
        float pv = EXP2(__builtin_fmaf(s[mf][r], CSC, -mC));
        p[mf*4+r] = pv; ps += pv;
      }
    ps += __shfl_xor(ps, 16);
    ps += __shfl_xor(ps, 32);
    lsum = lsum*alpha + ps;
    mrun = mnew;
    #pragma unroll
    for(int mf=0;mf<4;++mf) o[mf] *= alpha;

    // --- pack P to bf16 pairs: pk[mf*2+j] = (r=2j, r=2j+1) ---
    u32 pk[8];
    #pragma unroll
    for(int mf=0;mf<4;++mf){
      pk[mf*2+0] = cvtpk(p[mf*4+0], p[mf*4+1]);
      pk[mf*2+1] = cvtpk(p[mf*4+2], p[mf*4+3]);
    }

    // --- PV: O^T += V^T * P^T ; B-frag gathered via ds_bpermute ---
    int aA = ((c + 32*(g & 1)) << 2);
    int aB = aA + 64;
    bool hi = (g >= 2);
    #pragma unroll
    for(int t2=0; t2<2; ++t2){
      u32 b0a = __builtin_amdgcn_ds_bpermute(aA, (int)pk[4*t2 + 0]);
      u32 b0b = __builtin_amdgcn_ds_bpermute(aA, (int)pk[4*t2 + 2]);
      u32 b1a = __builtin_amdgcn_ds_bpermute(aA, (int)pk[4*t2 + 1]);
      u32 b1b = __builtin_amdgcn_ds_bpermute(aA, (int)pk[4*t2 + 3]);
      u32 b2a = __builtin_amdgcn_ds_bpermute(aB, (int)pk[4*t2 + 0]);
      u32 b2b = __builtin_amdgcn_ds_bpermute(aB, (int)pk[4*t2 + 2]);
      u32 b3a = __builtin_amdgcn_ds_bpermute(aB, (int)pk[4*t2 + 1]);
      u32 b3b = __builtin_amdgcn_ds_bpermute(aB, (int)pk[4*t2 + 3]);
      i32x4 bi;
      bi[0] = (int)(hi ? b0b : b0a);
      bi[1] = (int)(hi ? b1b : b1a);
      bi[2] = (int)(hi ? b2b : b2a);
      bi[3] = (int)(hi ? b3b : b3a);
      bf16x8 pf = __builtin_bit_cast(bf16x8, bi);
      __builtin_amdgcn_s_setprio(1);
      #pragma unroll
      for(int mf=0; mf<4; ++mf){
        int row = 16*mf + c;                 // row = d
        int sl  = (4*t2 + g) ^ (row & 7);
        bf16x8 vf = *(const bf16x8*)&Vl[bb*4096 + row*64 + sl*8];
        o[mf] = __builtin_amdgcn_mfma_f32_16x16x32_bf16(vf, pf, o[mf], 0,0,0);
      }
      __builtin_amdgcn_s_setprio(0);
    }
    __syncthreads();
  }

  // --- epilogue: O^T regs (all q=c) -> LDS -> coalesced bf16 store ---
  float inv = 1.f / lsum;
  __syncthreads();   // all K/V reads + in-flight loads drained before Ol reuse
  #pragma unroll
  for(int mf=0;mf<4;++mf)
    #pragma unroll
    for(int r=0;r<4;++r){
      int d = 16*mf + 4*g + r;
      Ol[w*1280 + c*80 + d] = f2bf(o[mf][r]*inv);
    }
  __syncthreads();
  {
    int q = l >> 2, dc = l & 3;
    u16x8 o0 = *(u16x8*)&Ol[w*1280 + q*80 + dc*16];
    u16x8 o1 = *(u16x8*)&Ol[w*1280 + q*80 + dc*16 + 8];
    u16* dst = ya + (size_t)(b*S_ + q0 + q)*D_ + h*HD_ + dc*16;
    *(u16x8*)dst       = o0;
    *(u16x8*)(dst + 8) = o1;
  }
}

extern "C" void kernel_launch(void* const* d_in, const int* in_sizes, int n_in,
                              void* d_out, int out_size, void* d_ws, size_t ws_size,
                              hipStream_t stream){
  const float* x      = (const float*)d_in[0];
  const float* w_attn = (const float*)d_in[1];
  const float* b_attn = (const float*)d_in[2];
  const float* w_proj = (const float*)d_in[3];
  const float* b_proj = (const float*)d_in[4];
  float* out = (float*)d_out;

  char* ws = (char*)d_ws;
  u16* xb  = (u16*)ws;  ws += (size_t)TOK*D_*2;   // 16.8 MB
  u16* waT = (u16*)ws;  ws += (size_t)D3*D_*2;    //  6.3 MB
  u16* wpT = (u16*)ws;  ws += (size_t)D_*D_*2;    //  2.1 MB
  u16* qkv = (u16*)ws;  ws += (size_t)TOK*D3*2;   // 50.3 MB
  u16* Vt  = (u16*)ws;  ws += (size_t)TOK*D_*2;   // 16.8 MB
  u16* ya  = (u16*)ws;  ws += (size_t)TOK*D_*2;   // 16.8 MB  (total ~109 MB)

  castx_kernel<<<TOK*D_/(256*8), 256, 0, stream>>>(x, xb);
  tcast_kernel<<<dim3(D_/32, D3/32), 256, 0, stream>>>(w_attn, waT, D_, D3);
  tcast_kernel<<<dim3(D_/32, D_/32), 256, 0, stream>>>(w_proj, wpT, D_, D_);
  gemm_kernel<false><<<dim3(TOK/128, D3/128), 256, 0, stream>>>(xb, waT, b_attn, qkv, D3, D_);
  vtrans_kernel<<<dim3(S_/64, NH_, B_), 256, 0, stream>>>(qkv, Vt);
  attn_kernel<<<dim3(S_/128, NH_, B_), 512, 0, stream>>>(qkv, Vt, ya);
  gemm_kernel<true><<<dim3(TOK/128, D_/128), 256, 0, stream>>>(ya, wpT, b_proj, out, D_, D_);
}